// Round 8
// baseline (138.891 us; speedup 1.0000x reference)
//
#include <hip/hip_runtime.h>

#define NQ 50000
#define NS 50000
#define MNB 32
#define KP 15
#define QPB 32              // queries per block (2 per wave, 16 waves)
#define NBLK 1563           // ceil(NQ/QPB)

// workspace layout (bytes)
#define WBF_BYTES 131072                  // swizzled W, K padded to 1024
#define XBF_BYTES ((NS + 1) * 128)        // 6400128: bf16 x rows + zero shadow row
#define SP2_OFF   (WBF_BYTES + XBF_BYTES) // 6531200: sp copy + 1e6 shadow row

typedef __bf16 bf16x8 __attribute__((ext_vector_type(8)));
typedef float  f32x4  __attribute__((ext_vector_type(4)));

__device__ __forceinline__ unsigned short bf1(float f) {
    union { __bf16 h; unsigned short s; } r; r.h = (__bf16)f; return r.s;
}
__device__ __forceinline__ unsigned pk2(float a, float b) {   // v_cvt_pk_bf16_f32
    union { __bf16 h[2]; unsigned u; } r;
    r.h[0] = (__bf16)a; r.h[1] = (__bf16)b; return r.u;
}

// v_perm_b32 selectors: pool = {src1 bytes 0-3, src0 bytes 4-7}; builtin(a,b,s)
// has b as src1 (bytes 0-3). LO picks lo16 of b then lo16 of a; HI the hi16s.
#define PERM_LO 0x05040100u
#define PERM_HI 0x07060302u

// ---------------------------------------------------------------------------
// Prep:
//  blocks [0,32):     W [960][64] f32 -> bf16 wBf, K padded to 1024, chunk
//                     c = cc*2048 + ks*64 + qq*16 + cl holds W[ks*32+qq*8+j][cc*16+cl].
//  blocks [32,1595):  x -> bf16 rows xBf (8 ch / thread) + ZERO shadow row NS.
//  blocks [1595,...): sp -> sp2 copy + shadow row NS = 1e6 (kills all masking
//                     in the fused kernel: id==NS reads shadow coords -> w=0,
//                     and gathers read the zero xBf row).
// ---------------------------------------------------------------------------
__global__ __launch_bounds__(256) void conv_prep(const float* __restrict__ W,
                                                 uint4* __restrict__ wBf,
                                                 const float* __restrict__ x,
                                                 uint4* __restrict__ xBf,
                                                 const float* __restrict__ sp,
                                                 float* __restrict__ sp2) {
    const int b = blockIdx.x;
    if (b < 32) {
        const int c = b * 256 + threadIdx.x;          // < 8192
        const int cl = c & 15, qq = (c >> 4) & 3, ks = (c >> 6) & 31, cc = c >> 11;
        const int k0 = ks * 32 + qq * 8;              // kappa base
        const int o  = cc * 16 + cl;                  // out column
        union { unsigned short s[8]; uint4 u; } pk;
        #pragma unroll
        for (int j = 0; j < 8; ++j)
            pk.s[j] = (k0 + j < KP * 64) ? bf1(W[(size_t)(k0 + j) * 64 + o])
                                         : (unsigned short)0;
        wBf[c] = pk.u;
    } else if (b < 1595) {
        const int t = (b - 32) * 256 + threadIdx.x;   // uint4 chunk = 8 channels
        if (t < (NS * 64) / 8) {                      // 400000 real chunks
            const float4* __restrict__ x4 = (const float4*)x;
            const float4 a = x4[t * 2];
            const float4 c2 = x4[t * 2 + 1];
            uint4 o;
            o.x = pk2(a.x, a.y);  o.y = pk2(a.z, a.w);
            o.z = pk2(c2.x, c2.y); o.w = pk2(c2.z, c2.w);
            xBf[t] = o;
        } else if (t < (NS * 64) / 8 + 8) {           // zero shadow row NS
            xBf[t] = (uint4){0u, 0u, 0u, 0u};
        }
    } else {
        const int i = (b - 1595) * 256 + threadIdx.x;
        if (i < (NS + 1) * 3)
            sp2[i] = (i < NS * 3) ? sp[i] : 1e6f;     // shadow row = 1e6
    }
}

// ---------------------------------------------------------------------------
// Fused KPConv, swapped-operand + LDS-free front-end: 1024 threads, 32
// queries/block (2 per wave, sequential), grid 1563 one-shot.
// Per query g = 2wv+gg (n wave-uniform -> qp via scalar loads):
//   8 independent chains, lane (cl,q), j=0..7 (neighbor 4j+q):
//     id  = nb[n*32+4j+q]      (16-lane broadcast, saddr + imm offset, nt)
//     sp2 row id (dwordx3)     (no mask: shadow row NS = 1e6 -> w=0)
//     r[j] = xBf row id        (no mask: shadow row NS = zeros)
//     w[j] = max(1-|s-(q+kp_cl)|,0)   (kq folded: 3 subs; kpt15 phantom@1e9)
//   This replaces R7's stage + rc4 LDS round-trip: -16 ds_read_b128/wave,
//   -1 ds_write, -stage VALU/divergence; VMEM instr +, but all saddr-form.
// Phase B (R7 verbatim): v_perm repack -> A-frag feats, B-frag = w; 4 MFMAs
//   (D^T = feats^T x w^T); acc -> wt[g][kappa] as 2 ds_write_b128, XOR key
//   ((g&7)^(cl&7))<<4 (conflict-free b128 floor).
// GEMM (R7 verbatim): out[32][64] = wt[32][1024] @ wBf, all 16 waves
//   (h = K-half, 8 out-tiles), halves reduced via sm.red; nt out stores.
// LDS = 65536 (wt) + 8192 (red) = 73728 B -> 2 blocks/CU.
// ---------------------------------------------------------------------------
__global__ __launch_bounds__(1024, 8) void kpconv_fused(
    const float* __restrict__ qp, const float* __restrict__ sp2,
    const int* __restrict__ nb, const uint2* __restrict__ xb,
    const float* __restrict__ kpts, const uint4* __restrict__ wBf,
    float* __restrict__ out)
{
    __shared__ struct {
        __align__(16) unsigned short wt[QPB * 1024];   // 65536 B, swizzled
        __align__(16) f32x4 red[8][64];                //  8192 B GEMM partials
    } sm;                                              // 73728 B

    const int tid  = threadIdx.x;
    const int lane = tid & 63;
    const int wv   = __builtin_amdgcn_readfirstlane(tid >> 6);  // 0-15
    const int cl = lane & 15, q = lane >> 4;
    const int n0 = blockIdx.x * QPB;

    // per-lane kernel point; cl==15 -> phantom at 1e9 (w==0 for any real r)
    const float kx = (cl < KP) ? kpts[cl * 3 + 0] : 1e9f;
    const float ky = (cl < KP) ? kpts[cl * 3 + 1] : 1e9f;
    const float kz = (cl < KP) ? kpts[cl * 3 + 2] : 1e9f;

    const f32x4 zero = (f32x4){0.f, 0.f, 0.f, 0.f};

    #pragma unroll 1
    for (int gg = 0; gg < 2; ++gg) {
        const int g = wv * 2 + gg;
        const int n = n0 + g;
        const int nc = (n < NQ) ? n : (NQ - 1);        // uniform clamp (out is
                                                       // guarded at the write)
        const float qx = qp[nc * 3 + 0];               // wave-uniform: s_load
        const float qy = qp[nc * 3 + 1];
        const float qz = qp[nc * 3 + 2];
        const float kqx = kx + qx, kqy = ky + qy, kqz = kz + qz;
        const int* __restrict__ nbq = nb + nc * MNB;

        // ---- 8 independent chains: nb -> sp2 -> w ; xb gather in flight
        float w[8]; uint2 r[8];
        #pragma unroll
        for (int j = 0; j < 8; ++j) {
            const unsigned id = (unsigned)__builtin_nontemporal_load(&nbq[4 * j + q]);
            const unsigned so = id * 3u;
            const float sx = sp2[so + 0];
            const float sy = sp2[so + 1];
            const float sz = sp2[so + 2];
            r[j] = xb[id * 16u + (unsigned)cl];
            const float dx = sx - kqx, dy = sy - kqy, dz = sz - kqz;
            const float d2 = dx * dx + dy * dy + dz * dz;
            w[j] = fmaxf(1.0f - __builtin_amdgcn_sqrtf(d2), 0.0f);
        }

        // ---- phase B: repack + 4 MFMAs + swizzled wt store (R7 verbatim)
        union { uint4 u; bf16x8 v; } wf;           // B-fragment: w[cl][slot 8q+j]
        wf.u.x = pk2(w[0], w[1]); wf.u.y = pk2(w[2], w[3]);
        wf.u.z = pk2(w[4], w[5]); wf.u.w = pk2(w[6], w[7]);
        union { uint4 u; bf16x8 v; } af[4];        // A-frag: feat[4j+q][cl*4+cb]
        #pragma unroll
        for (int pr = 0; pr < 4; ++pr) {
            const uint2 e = r[2 * pr], o = r[2 * pr + 1];
            ((unsigned*)&af[0].u)[pr] = __builtin_amdgcn_perm(o.x, e.x, PERM_LO);
            ((unsigned*)&af[1].u)[pr] = __builtin_amdgcn_perm(o.x, e.x, PERM_HI);
            ((unsigned*)&af[2].u)[pr] = __builtin_amdgcn_perm(o.y, e.y, PERM_LO);
            ((unsigned*)&af[3].u)[pr] = __builtin_amdgcn_perm(o.y, e.y, PERM_HI);
        }
        f32x4 acc[4];
        #pragma unroll
        for (int cb = 0; cb < 4; ++cb)
            acc[cb] = __builtin_amdgcn_mfma_f32_16x16x32_bf16(af[cb].v, wf.v, zero, 0, 0, 0);
        // acc[cb][i] = weighted[k=cl][ch=(q*4+i)*4+cb] -> kappa = cl*64+q*16+i*4+cb
        unsigned pkd[8];
        #pragma unroll
        for (int i = 0; i < 4; ++i) {
            pkd[2 * i]     = pk2(acc[0][i], acc[1][i]);
            pkd[2 * i + 1] = pk2(acc[2][i], acc[3][i]);
        }
        const unsigned key = (unsigned)(((g & 7) ^ (cl & 7)) << 4);
        char* base = (char*)sm.wt + g * 2048;
        const unsigned i0 = (unsigned)(cl * 128 + q * 32);
        *(uint4*)(base + ((i0)      ^ key)) = (uint4){pkd[0], pkd[1], pkd[2], pkd[3]};
        *(uint4*)(base + ((i0 + 16) ^ key)) = (uint4){pkd[4], pkd[5], pkd[6], pkd[7]};
    }

    __syncthreads();                               // barrier 1 of 2

    // ---- GEMM: out[32][64] = wt[32][1024] @ W, all 16 waves (R7 verbatim)
    const int h  = wv >> 3;                        // K-half
    const int tl = wv & 7;                         // out-tile
    const int rc = tl >> 2, cc = tl & 3;
    const char* abase = (const char*)sm.wt + (rc * 16 + cl) * 2048;
    const unsigned akey = (unsigned)((cl & 7) << 4);
    const uint4* wb = wBf + (((cc * 32 + h * 16) * 4 + q) * 16 + cl);
    f32x4 d0 = zero, d1 = zero;
    #pragma unroll 4
    for (int it = 0; it < 16; it += 2) {
        const int ks0 = h * 16 + it;               // even
        const unsigned kk  = (unsigned)((((ks0 >> 1) & 7)) << 4);
        const unsigned ia0 = (unsigned)(ks0 * 64 + q * 16);
        const bf16x8 a0 = *(const bf16x8*)(abase + ((ia0)      ^ akey ^ kk));
        const bf16x8 a1 = *(const bf16x8*)(abase + ((ia0 + 64) ^ akey ^ kk));
        union { uint4 u; bf16x8 v; } b0, b1;
        b0.u = wb[it * 64];
        b1.u = wb[it * 64 + 64];
        d0 = __builtin_amdgcn_mfma_f32_16x16x32_bf16(a0, b0.v, d0, 0, 0, 0);
        d1 = __builtin_amdgcn_mfma_f32_16x16x32_bf16(a1, b1.v, d1, 0, 0, 0);
    }
    f32x4 dd = d0 + d1;
    if (h == 1) sm.red[tl][lane] = dd;             // partials
    __syncthreads();                               // barrier 2 of 2
    if (h == 0) {
        dd += sm.red[tl][lane];
        #pragma unroll
        for (int i = 0; i < 4; ++i) {
            const int n = n0 + rc * 16 + q * 4 + i;
            if (n < NQ)
                __builtin_nontemporal_store(dd[i], &out[(size_t)n * 64 + cc * 16 + cl]);
        }
    }
}

// ---------------------------------------------------------------------------
extern "C" void kernel_launch(void* const* d_in, const int* in_sizes, int n_in,
                              void* d_out, int out_size, void* d_ws, size_t ws_size,
                              hipStream_t stream) {
    const float* qp   = (const float*)d_in[0];
    const float* sp   = (const float*)d_in[1];
    const int*   nb   = (const int*)d_in[2];
    const float* x    = (const float*)d_in[3];
    const float* kpts = (const float*)d_in[4];
    const float* W    = (const float*)d_in[5];
    float* out = (float*)d_out;

    uint4* wBf = (uint4*)d_ws;                          // swizzled W (K=1024)
    uint4* xBf = (uint4*)((char*)d_ws + WBF_BYTES);     // bf16 x + zero shadow
    float* sp2 = (float*)((char*)d_ws + SP2_OFF);       // sp + 1e6 shadow

    const int spBlocks = ((NS + 1) * 3 + 255) / 256;    // 587
    hipLaunchKernelGGL(conv_prep, dim3(1595 + spBlocks), dim3(256), 0, stream,
                       W, wBf, x, xBf, sp, sp2);
    hipLaunchKernelGGL(kpconv_fused, dim3(NBLK), dim3(1024), 0, stream,
                       qp, sp2, nb, (const uint2*)xBf, kpts, wBf, out);
}

// Round 9
// 122.167 us; speedup vs baseline: 1.1369x; 1.1369x over previous
//
#include <hip/hip_runtime.h>

#define NQ 50000
#define NS 50000
#define MNB 32
#define KP 15
#define QPB 16              // queries per block (2 per wave, 8 waves)
#define NBLK 3125           // NQ / QPB exact -> zero bounds checks

typedef __bf16 bf16x8 __attribute__((ext_vector_type(8)));
typedef float  f32x4  __attribute__((ext_vector_type(4)));

__device__ __forceinline__ unsigned short bf1(float f) {
    union { __bf16 h; unsigned short s; } r; r.h = (__bf16)f; return r.s;
}
__device__ __forceinline__ unsigned pk2(float a, float b) {   // v_cvt_pk_bf16_f32
    union { __bf16 h[2]; unsigned u; } r;
    r.h[0] = (__bf16)a; r.h[1] = (__bf16)b; return r.u;
}

// v_perm_b32 selectors: pool = {src1 bytes 0-3, src0 bytes 4-7}; builtin(a,b,s)
// has b as src1 (bytes 0-3). LO picks lo16 of b then lo16 of a; HI the hi16s.
#define PERM_LO 0x05040100u
#define PERM_HI 0x07060302u

// ---------------------------------------------------------------------------
// Prep (R7 verbatim):
//  blocks [0,32):    W [960][64] f32 -> bf16 wBf, K padded to 1024, chunk
//                    c = cc*2048 + ks*64 + qq*16 + cl holds W[ks*32+qq*8+j][cc*16+cl].
//  blocks [32,1595): x -> bf16 rows xBf (8 ch / thread).
// ---------------------------------------------------------------------------
__global__ __launch_bounds__(256) void conv_prep(const float* __restrict__ W,
                                                 uint4* __restrict__ wBf,
                                                 const float* __restrict__ x,
                                                 uint4* __restrict__ xBf) {
    const int b = blockIdx.x;
    if (b < 32) {
        const int c = b * 256 + threadIdx.x;          // < 8192
        const int cl = c & 15, qq = (c >> 4) & 3, ks = (c >> 6) & 31, cc = c >> 11;
        const int k0 = ks * 32 + qq * 8;              // kappa base
        const int o  = cc * 16 + cl;                  // out column
        union { unsigned short s[8]; uint4 u; } pk;
        #pragma unroll
        for (int j = 0; j < 8; ++j)
            pk.s[j] = (k0 + j < KP * 64) ? bf1(W[(size_t)(k0 + j) * 64 + o])
                                         : (unsigned short)0;
        wBf[c] = pk.u;
    } else {
        const int t = (b - 32) * 256 + threadIdx.x;   // uint4 chunk = 8 channels
        if (t < (NS * 64) / 8) {                      // 400000
            const float4* __restrict__ x4 = (const float4*)x;
            const float4 a = x4[t * 2];
            const float4 c2 = x4[t * 2 + 1];
            uint4 o;
            o.x = pk2(a.x, a.y);  o.y = pk2(a.z, a.w);
            o.z = pk2(c2.x, c2.y); o.w = pk2(c2.z, c2.w);
            xBf[t] = o;
        }
    }
}

// ---------------------------------------------------------------------------
// Fused KPConv, swapped-operand (R7) at HALF block size: 512 threads, 16
// queries/block (2 per wave, sequential), grid 3125 exact.  Per-query work
// is IDENTICAL to R7 (4 stage-1 MFMAs, 8 GEMM MFMAs, 8 KB wBf reads); what
// changes is 4 barrier domains per CU instead of 2 -- one block's barrier
// drain overlaps three other blocks' gather phases.
// Stage:  lane (gh,m) loads nb/qp/sp for query 2wv+gh -> rc4[g][m]
//   (same-wave produce/consume, no barrier).
// Per query g = 2wv+gg (unroll 1, no spills):
//   phase A: lane (cl,q) reads rc4[g][4j+q] (b128, 16-lane broadcast),
//   w[j] = max(1-|r-kp_cl|,0) (kpt15 phantom via gate), gather r[j] issued
//   in-loop from rc.w.
//   phase B: v_perm repack -> A-frag feats; B-frag = w; 4 MFMAs
//   (D^T = feats^T x w^T); acc -> wt[g][kappa=cl*64+q*16+i*4+cb] as 2
//   ds_write_b128, XOR key ((g&7)^(cl&7))<<4 (conflict-free b128 floor).
// GEMM: out[16][64] = wt[16][1024] @ wBf, all 8 waves: (h=wv>>2 K-half,
//   cc=wv&3 col-chunk), 16 MFMAs each; halves reduced via red (aliases rc4).
// LDS = 32768 (wt) + 8192 (rc4|red) = 40960 B -> 4 blocks/CU (160 KiB exact).
// ---------------------------------------------------------------------------
__global__ __launch_bounds__(512, 8) void kpconv_fused(
    const float* __restrict__ qp, const float* __restrict__ sp,
    const int* __restrict__ nb, const uint2* __restrict__ xb,
    const float* __restrict__ kpts, const uint4* __restrict__ wBf,
    float* __restrict__ out)
{
    __shared__ struct {
        __align__(16) unsigned short wt[QPB * 1024];   // 32768 B, swizzled
        union {
            float4 rc4[QPB][MNB];                      // 8192 B staging
            f32x4  red[4][64];                         // 4096 B GEMM partials
        } u;
    } sm;                                              // 40960 B

    const int tid  = threadIdx.x;
    const int lane = tid & 63;
    const int wv   = __builtin_amdgcn_readfirstlane(tid >> 6);  // 0-7
    const int cl = lane & 15, q = lane >> 4;
    const int n0 = blockIdx.x * QPB;

    // per-lane kernel point (k = cl, clamped; cl==15 is the zero pad column)
    const int   kidx = (cl < KP) ? cl : (KP - 1);
    const float kx = kpts[kidx * 3 + 0];
    const float ky = kpts[kidx * 3 + 1];
    const float kz = kpts[kidx * 3 + 2];
    const float gate = (cl < KP) ? 1.0f : 0.0f;

    // ---- stage: query g = 2wv+gh, neighbor m (same-wave ordering, no barrier)
    {
        const int m  = lane & 31, gh = lane >> 5;
        const int n  = n0 + wv * 2 + gh;               // always < NQ (exact grid)
        const int id = nb[n * MNB + m];
        const float qx = qp[n * 3 + 0], qy = qp[n * 3 + 1], qz = qp[n * 3 + 2];
        float sx = 1e6f, sy = 1e6f, sz = 1e6f;
        if (id < NS) { sx = sp[id*3+0]; sy = sp[id*3+1]; sz = sp[id*3+2]; }
        const float rx = sx - qx, ry = sy - qy, rz = sz - qz;
        const int idc = (id < NS) ? id : 0;    // w==0 nullifies clamped gathers
        sm.u.rc4[wv * 2 + gh][m] = (float4){rx, ry, rz, __int_as_float(idc)};
    }

    // ---- per query: phase A (+ fused gather issue) then phase B; unroll 1
    const f32x4 zero = (f32x4){0.f, 0.f, 0.f, 0.f};
    #pragma unroll 1
    for (int gg = 0; gg < 2; ++gg) {
        const int g = wv * 2 + gg;
        float w[8]; uint2 r[8];
        #pragma unroll
        for (int j = 0; j < 8; ++j) {
            const float4 rc = sm.u.rc4[g][4 * j + q];
            const float dx = rc.x - kx, dy = rc.y - ky, dz = rc.z - kz;
            const float d2 = dx * dx + dy * dy + dz * dz;
            w[j] = fmaxf(1.0f - __builtin_amdgcn_sqrtf(d2), 0.0f) * gate;
            r[j] = xb[(size_t)__float_as_uint(rc.w) * 16 + cl];   // issue now
        }
        union { uint4 u; bf16x8 v; } wf;           // B-fragment: w[cl][slot 8q+j]
        wf.u.x = pk2(w[0], w[1]); wf.u.y = pk2(w[2], w[3]);
        wf.u.z = pk2(w[4], w[5]); wf.u.w = pk2(w[6], w[7]);
        union { uint4 u; bf16x8 v; } af[4];        // A-frag: feat[4j+q][cl*4+cb]
        #pragma unroll
        for (int pr = 0; pr < 4; ++pr) {
            const uint2 e = r[2 * pr], o = r[2 * pr + 1];
            ((unsigned*)&af[0].u)[pr] = __builtin_amdgcn_perm(o.x, e.x, PERM_LO);
            ((unsigned*)&af[1].u)[pr] = __builtin_amdgcn_perm(o.x, e.x, PERM_HI);
            ((unsigned*)&af[2].u)[pr] = __builtin_amdgcn_perm(o.y, e.y, PERM_LO);
            ((unsigned*)&af[3].u)[pr] = __builtin_amdgcn_perm(o.y, e.y, PERM_HI);
        }
        f32x4 acc[4];
        #pragma unroll
        for (int cb = 0; cb < 4; ++cb)
            acc[cb] = __builtin_amdgcn_mfma_f32_16x16x32_bf16(af[cb].v, wf.v, zero, 0, 0, 0);
        // acc[cb][i] = weighted[k=cl][ch=(q*4+i)*4+cb] -> kappa = cl*64+q*16+i*4+cb
        unsigned pkd[8];
        #pragma unroll
        for (int i = 0; i < 4; ++i) {
            pkd[2 * i]     = pk2(acc[0][i], acc[1][i]);
            pkd[2 * i + 1] = pk2(acc[2][i], acc[3][i]);
        }
        const unsigned key = (unsigned)(((g & 7) ^ (cl & 7)) << 4);
        char* base = (char*)sm.wt + g * 2048;
        const unsigned i0 = (unsigned)(cl * 128 + q * 32);
        *(uint4*)(base + ((i0)      ^ key)) = (uint4){pkd[0], pkd[1], pkd[2], pkd[3]};
        *(uint4*)(base + ((i0 + 16) ^ key)) = (uint4){pkd[4], pkd[5], pkd[6], pkd[7]};
    }

    __syncthreads();                               // barrier 1 of 2

    // ---- GEMM: out[16][64] = wt[16][1024] @ W, all 8 waves
    const int h  = wv >> 2;                        // K-half
    const int cc = wv & 3;                         // col chunk
    const char* abase = (const char*)sm.wt + cl * 2048;
    const unsigned akey = (unsigned)((cl & 7) << 4);
    const uint4* wb = wBf + (cc * 2048 + h * 1024 + q * 16 + cl);
    f32x4 d0 = zero, d1 = zero;
    #pragma unroll 4
    for (int it = 0; it < 16; it += 2) {
        const int ks0 = h * 16 + it;               // even
        const unsigned kk  = (unsigned)((((ks0 >> 1) & 7)) << 4);
        const unsigned ia0 = (unsigned)(ks0 * 64 + q * 16);
        const bf16x8 a0 = *(const bf16x8*)(abase + ((ia0)      ^ akey ^ kk));
        const bf16x8 a1 = *(const bf16x8*)(abase + ((ia0 + 64) ^ akey ^ kk));
        union { uint4 u; bf16x8 v; } b0, b1;
        b0.u = wb[it * 64];
        b1.u = wb[it * 64 + 64];
        d0 = __builtin_amdgcn_mfma_f32_16x16x32_bf16(a0, b0.v, d0, 0, 0, 0);
        d1 = __builtin_amdgcn_mfma_f32_16x16x32_bf16(a1, b1.v, d1, 0, 0, 0);
    }
    f32x4 dd = d0 + d1;
    if (h == 1) sm.u.red[cc][lane] = dd;           // partials into dead rc4
    __syncthreads();                               // barrier 2 of 2
    if (h == 0) {
        dd += sm.u.red[cc][lane];
        #pragma unroll
        for (int i = 0; i < 4; ++i) {
            const int n = n0 + q * 4 + i;          // rows 0-15, always < NQ
            out[(size_t)n * 64 + cc * 16 + cl] = dd[i];
        }
    }
}

// ---------------------------------------------------------------------------
extern "C" void kernel_launch(void* const* d_in, const int* in_sizes, int n_in,
                              void* d_out, int out_size, void* d_ws, size_t ws_size,
                              hipStream_t stream) {
    const float* qp   = (const float*)d_in[0];
    const float* sp   = (const float*)d_in[1];
    const int*   nb   = (const int*)d_in[2];
    const float* x    = (const float*)d_in[3];
    const float* kpts = (const float*)d_in[4];
    const float* W    = (const float*)d_in[5];
    float* out = (float*)d_out;

    uint4* wBf = (uint4*)d_ws;                          // 131072 B swizzled W (K=1024)
    uint4* xBf = (uint4*)((char*)d_ws + 131072);        // 6.4 MB bf16 features

    hipLaunchKernelGGL(conv_prep, dim3(32 + (NS * 64 / 8 + 255) / 256), dim3(256),
                       0, stream, W, wBf, x, xBf);
    hipLaunchKernelGGL(kpconv_fused, dim3(NBLK), dim3(512), 0, stream,
                       qp, sp, nb, (const uint2*)xBf, kpts, wBf, out);
}